// Round 10
// baseline (380.050 us; speedup 1.0000x reference)
//
#include <hip/hip_runtime.h>
#include <hip/hip_bf16.h>
#include <cstdint>

// ---------------------------------------------------------------------------
// InitialContextualNodeModel — one-pass bin -> per-bucket fixed-point LDS
//   accumulate (native int ds_add) -> MFMA bf16 MLP
//   keys g in [0,3N): s=0 fwd (future), s=1 frame (early+later), s=2 bwd (past)
//   flow[n] = [ fwd_mean | frame_mean | bwd_mean ]  (192 bf16)
//   out = relu(flow @ W1 + b1) @ W2 + b2   (f32 out)
// Entry packed u32: (g & 63) << 20 | edge_id   (edge ids < 2^20)
// Fixed point: round(x * 2^19); |x|<=~6, deg<=~48 -> |sum| < 1.6e8 << 2^31.
// ---------------------------------------------------------------------------

#define D 64
#define R_BITS 6
#define R 64                  // keys per bucket
#define CAP 2048              // entry capacity per bucket (mean ~1024)
#define NB_MAX 4096           // max buckets (T <= 262144)
#define TILE_SRC 4096         // source edges per bin block (-> 8192 entries)
#define FXS 524288.0f         // 2^19
#define FXSI (1.0f / 524288.0f)

typedef __attribute__((ext_vector_type(8))) short bf16x8;
typedef __attribute__((ext_vector_type(4))) float f32x4;

__device__ inline unsigned short f2bf(float x) {   // round-to-nearest-even
    unsigned int u = __float_as_uint(x);
    unsigned int r = u + 0x7FFFu + ((u >> 16) & 1u);
    return (unsigned short)(r >> 16);
}

// ---- weight prep: W1[192][128]f32 -> W1T[128][192]bf16; W2 likewise --------
__global__ __launch_bounds__(256) void wconv_kernel(
    const float* __restrict__ W1, const float* __restrict__ W2,
    unsigned short* __restrict__ W1T, unsigned short* __restrict__ W2T)
{
    int i = blockIdx.x * 256 + threadIdx.x;
    if (i < 192 * 128) {
        int k = i >> 7, n = i & 127;
        W1T[n * 192 + k] = f2bf(W1[i]);
    }
    int j = i - 192 * 128;
    if (j >= 0 && j < 128 * 64) {
        int k = j >> 6, n = j & 63;
        W2T[n * 128 + k] = f2bf(W2[j]);
    }
}

// ---- bin: LDS-aggregated one-pass scatter into fixed-cap buckets -----------
__global__ __launch_bounds__(256) void bin_kernel(
    const int* __restrict__ ei, const int* __restrict__ sfi,
    int* __restrict__ bucket_cur, unsigned int* __restrict__ binned,
    int E, int Es, int N, int NB)
{
    __shared__ int hist[NB_MAX];      // per-block count, then rank cursor
    __shared__ int base_sh[NB_MAX];   // within-bucket reserved base

    int t = threadIdx.x;
    int tile0 = blockIdx.x * TILE_SRC;

    for (int b = t; b < NB; b += 256) hist[b] = 0;
    __syncthreads();

    // phase 1: histogram of bucket ids for this tile
#pragma unroll
    for (int u = 0; u < 16; ++u) {
        int src = tile0 + u * 256 + t;
        if (src < E) {
            atomicAdd(&hist[((unsigned)ei[E + src]) >> R_BITS], 1);
            atomicAdd(&hist[((unsigned)(2 * N + ei[src])) >> R_BITS], 1);
        } else if (src < E + Es) {
            int e = src - E;
            atomicAdd(&hist[((unsigned)(N + sfi[e])) >> R_BITS], 1);
            atomicAdd(&hist[((unsigned)(N + sfi[Es + e])) >> R_BITS], 1);
        }
    }
    __syncthreads();

    // phase 2: reserve per-bucket ranges; reset hist for ranking
    for (int b = t; b < NB; b += 256) {
        int c = hist[b];
        base_sh[b] = (c > 0) ? atomicAdd(&bucket_cur[b], c) : 0;
        hist[b] = 0;
    }
    __syncthreads();

    // phase 3: rank + write packed entries (per-(block,bucket) runs)
#pragma unroll
    for (int u = 0; u < 16; ++u) {
        int src = tile0 + u * 256 + t;
        if (src >= E + Es) continue;
        unsigned int g0, g1, e;
        if (src < E) {
            e = (unsigned)src;
            g0 = (unsigned)ei[E + src];
            g1 = (unsigned)(2 * N + ei[src]);
        } else {
            e = (unsigned)(src - E);
            g0 = (unsigned)(N + sfi[e]);
            g1 = (unsigned)(N + sfi[Es + e]);
        }
        int b0 = g0 >> R_BITS, b1 = g1 >> R_BITS;
        int r0 = base_sh[b0] + atomicAdd(&hist[b0], 1);
        if (r0 < CAP) binned[(size_t)b0 * CAP + r0] = ((g0 & (R - 1)) << 20) | e;
        int r1 = base_sh[b1] + atomicAdd(&hist[b1], 1);
        if (r1 < CAP) binned[(size_t)b1 * CAP + r1] = ((g1 & (R - 1)) << 20) | e;
    }
}

// ---- per-bucket accumulate: 8 row-loads in flight/wave, int LDS atomics ----
__global__ __launch_bounds__(256) void bucket_accum_kernel(
    const float* __restrict__ edge_attr, const float* __restrict__ sf_attr,
    const unsigned int* __restrict__ binned, const int* __restrict__ bucket_cur,
    unsigned short* __restrict__ flow, int N, int T)
{
    __shared__ int acc[R * D];   // 16 KB fixed-point accumulators
    __shared__ int kcnt[R];

    int b = blockIdx.x;
    int t = threadIdx.x;
    int w = t >> 6;       // wave 0..3
    int j = t & 63;       // feature

    for (int i = t; i < R * D; i += 256) acc[i] = 0;
    if (t < R) kcnt[t] = 0;
    __syncthreads();

    int cb = bucket_cur[b];
    if (cb > CAP) cb = CAP;
    const size_t base = (size_t)b * CAP;

    // waves process interleaved chunks of 8 entries; 8 coalesced 256B row
    // reads in flight per wave before any accumulate.
    for (int i0 = w * 8; i0 < cb; i0 += 32) {
        int nm = cb - i0; if (nm > 8) nm = 8;    // wave-uniform
        unsigned int p[8];
#pragma unroll
        for (int m = 0; m < 8; ++m)
            if (m < nm) p[m] = binned[base + i0 + m];

        int gl[8]; float v[8];
#pragma unroll
        for (int m = 0; m < 8; ++m) {
            if (m < nm) {
                gl[m] = (int)(p[m] >> 20);
                unsigned int e = p[m] & 0xFFFFFu;
                int g = (b << R_BITS) + gl[m];
                const float* row = (g >= N && g < 2 * N)
                    ? (sf_attr + (size_t)e * D) : (edge_attr + (size_t)e * D);
                v[m] = row[j];
            }
        }
#pragma unroll
        for (int m = 0; m < 8; ++m) {
            if (m < nm) {
                atomicAdd(&acc[gl[m] * D + j], __float2int_rn(v[m] * FXS));
                if (j == 0) atomicAdd(&kcnt[gl[m]], 1);
            }
        }
    }
    __syncthreads();

    // write means: wave w -> keys [w*16, w*16+16), lane j = feature
    for (int kk = w * 16; kk < w * 16 + 16; ++kk) {
        int g = (b << R_BITS) + kk;
        if (g >= T) break;
        int s = (g >= 2 * N) ? 2 : ((g >= N) ? 1 : 0);
        int node = g - s * N;
        float inv = FXSI / fmaxf((float)kcnt[kk], 1.0f);
        flow[(size_t)node * 192 + s * D + j] = f2bf((float)acc[kk * D + j] * inv);
    }
}

// ---- MFMA MLP: 64 nodes/block, 4 waves ------------------------------------
// Layouts (gfx950 16x16x32 bf16, m89-verified): C/D col=lane&15,
// row=(lane>>4)*4+reg; A row=lane&15, k=(lane>>4)*8+j; B col=lane&15, same k.
#define MLP_NODES 64
#define FP 200     // ldsf row pitch (bf16): 400 B, 16B-aligned, 2-way bank alias
#define HP 136     // ldsh row pitch (bf16): 272 B

__global__ __launch_bounds__(256) void mlp_kernel(
    const unsigned short* __restrict__ flow,   // [N][192] bf16 means
    const unsigned short* __restrict__ W1T,    // [128][192] bf16
    const float* __restrict__ b1,
    const unsigned short* __restrict__ W2T,    // [64][128] bf16
    const float* __restrict__ b2,
    float* __restrict__ out, int N)
{
    __shared__ unsigned short ldsf[MLP_NODES * FP];  // 25.6 KB
    __shared__ unsigned short ldsh[MLP_NODES * HP];  // 17.4 KB

    int t = threadIdx.x;
    int nbase = blockIdx.x * MLP_NODES;

    // stage flow tile (64 nodes x 192 bf16 = 1536 x 16B)
    for (int i = t; i < 1536; i += 256) {
        int node = i / 24;
        int q    = i - node * 24;
        uint4 v = make_uint4(0u, 0u, 0u, 0u);
        if (nbase + node < N)
            v = *reinterpret_cast<const uint4*>(&flow[(size_t)(nbase + node) * 192 + q * 8]);
        *reinterpret_cast<uint4*>(&ldsf[node * FP + q * 8]) = v;
    }
    __syncthreads();

    int w   = t >> 6;
    int l   = t & 63;
    int m16 = l & 15;     // A row / B col / C col within 16x16 tile
    int kg  = l >> 4;     // k-group (k0 = kg*8), C row base = kg*4

    // ---- layer 1: M=64 (wave w owns nodes w*16..+15), Ncols=128, K=192 ----
    f32x4 acc[8];
#pragma unroll
    for (int i = 0; i < 8; ++i) acc[i] = (f32x4){0.f, 0.f, 0.f, 0.f};

#pragma unroll
    for (int kt = 0; kt < 6; ++kt) {
        bf16x8 a = *reinterpret_cast<const bf16x8*>(
            &ldsf[(w * 16 + m16) * FP + kt * 32 + kg * 8]);
#pragma unroll
        for (int nt = 0; nt < 8; ++nt) {
            bf16x8 bfr = *reinterpret_cast<const bf16x8*>(
                &W1T[(size_t)(nt * 16 + m16) * 192 + kt * 32 + kg * 8]);
            acc[nt] = __builtin_amdgcn_mfma_f32_16x16x32_bf16(a, bfr, acc[nt], 0, 0, 0);
        }
    }

    // relu + bias -> bf16 h in LDS (wave-private rows: no cross-wave dep)
#pragma unroll
    for (int nt = 0; nt < 8; ++nt) {
        int col = nt * 16 + m16;
        float bias = b1[col];
#pragma unroll
        for (int r = 0; r < 4; ++r) {
            int node = w * 16 + kg * 4 + r;
            ldsh[node * HP + col] = f2bf(fmaxf(acc[nt][r] + bias, 0.f));
        }
    }
    __syncthreads();

    // ---- layer 2: M=64, Ncols=64, K=128 ----
    f32x4 acc2[4];
#pragma unroll
    for (int i = 0; i < 4; ++i) acc2[i] = (f32x4){0.f, 0.f, 0.f, 0.f};

#pragma unroll
    for (int kt = 0; kt < 4; ++kt) {
        bf16x8 a = *reinterpret_cast<const bf16x8*>(
            &ldsh[(w * 16 + m16) * HP + kt * 32 + kg * 8]);
#pragma unroll
        for (int nt = 0; nt < 4; ++nt) {
            bf16x8 bfr = *reinterpret_cast<const bf16x8*>(
                &W2T[(size_t)(nt * 16 + m16) * 128 + kt * 32 + kg * 8]);
            acc2[nt] = __builtin_amdgcn_mfma_f32_16x16x32_bf16(a, bfr, acc2[nt], 0, 0, 0);
        }
    }

#pragma unroll
    for (int nt = 0; nt < 4; ++nt) {
        int col = nt * 16 + m16;
        float bias = b2[col];
#pragma unroll
        for (int r = 0; r < 4; ++r) {
            int node = nbase + w * 16 + kg * 4 + r;
            if (node < N)
                out[(size_t)node * D + col] = acc2[nt][r] + bias;
        }
    }
}

// ---------------------------------------------------------------------------
extern "C" void kernel_launch(void* const* d_in, const int* in_sizes, int n_in,
                              void* d_out, int out_size, void* d_ws, size_t ws_size,
                              hipStream_t stream)
{
    const int*   edge_index = (const int*)d_in[0];
    const float* edge_attr  = (const float*)d_in[1];
    const int*   sf_index   = (const int*)d_in[3];
    const float* sf_attr    = (const float*)d_in[4];
    const float* W1         = (const float*)d_in[5];
    const float* b1         = (const float*)d_in[6];
    const float* W2         = (const float*)d_in[7];
    const float* b2         = (const float*)d_in[8];
    float* out = (float*)d_out;

    int E  = in_sizes[0] / 2;
    int Es = in_sizes[3] / 2;
    int N  = out_size / D;
    int T  = 3 * N;                  // total keys
    int NB = (T + R - 1) / R;        // buckets (<= NB_MAX)

    unsigned short* flow = (unsigned short*)d_ws;          // N*192 bf16
    size_t flow_elems = (size_t)N * 192;

    unsigned int* binned = (unsigned int*)(flow + flow_elems);  // NB*CAP u32
    int* bucket_cur = (int*)(binned + (size_t)NB * CAP);        // NB
    unsigned short* W1T = (unsigned short*)(bucket_cur + NB_MAX); // 128*192
    unsigned short* W2T = W1T + 128 * 192;                        // 64*128

    hipMemsetAsync(bucket_cur, 0, (size_t)NB * sizeof(int), stream);

    wconv_kernel<<<(192 * 128 + 128 * 64 + 255) / 256, 256, 0, stream>>>(
        W1, W2, W1T, W2T);

    int nsrc = E + Es;
    int bin_blocks = (nsrc + TILE_SRC - 1) / TILE_SRC;

    bin_kernel<<<bin_blocks, 256, 0, stream>>>(
        edge_index, sf_index, bucket_cur, binned, E, Es, N, NB);

    bucket_accum_kernel<<<NB, 256, 0, stream>>>(
        edge_attr, sf_attr, binned, bucket_cur, flow, N, T);

    {
        int blocks = (N + MLP_NODES - 1) / MLP_NODES;
        mlp_kernel<<<blocks, 256, 0, stream>>>(flow, W1T, b1, W2T, b2, out, N);
    }
}

// Round 11
// 198.928 us; speedup vs baseline: 1.9105x; 1.9105x over previous
//
#include <hip/hip_runtime.h>
#include <hip/hip_bf16.h>
#include <cstdint>

// ---------------------------------------------------------------------------
// InitialContextualNodeModel — one-pass bin -> per-bucket LDS sort+gather(bf16)
//   -> MFMA bf16 MLP      (restores R9 structure; gather at 512 threads)
//   keys g in [0,3N): s=0 fwd (future), s=1 frame (early+later), s=2 bwd (past)
//   flow[n] = [ fwd_mean | frame_mean | bwd_mean ]  (192 bf16)
//   out = relu(flow @ W1 + b1) @ W2 + b2   (f32 out)
// Entry packed u32: (g & 63) << 20 | edge_id   (edge ids < 2^20)
// ---------------------------------------------------------------------------

#define D 64
#define R_BITS 6
#define R 64                  // keys per bucket
#define CAP 2048              // entry capacity per bucket (mean ~1024)
#define NB_MAX 4096           // max buckets (T <= 262144)
#define TILE_SRC 4096         // source edges per bin block (-> 8192 entries)

typedef __attribute__((ext_vector_type(8))) short bf16x8;
typedef __attribute__((ext_vector_type(4))) float f32x4;

__device__ inline unsigned short f2bf(float x) {   // round-to-nearest-even
    unsigned int u = __float_as_uint(x);
    unsigned int r = u + 0x7FFFu + ((u >> 16) & 1u);
    return (unsigned short)(r >> 16);
}

// ---- weight prep: W1[192][128]f32 -> W1T[128][192]bf16; W2 likewise --------
__global__ __launch_bounds__(256) void wconv_kernel(
    const float* __restrict__ W1, const float* __restrict__ W2,
    unsigned short* __restrict__ W1T, unsigned short* __restrict__ W2T)
{
    int i = blockIdx.x * 256 + threadIdx.x;
    if (i < 192 * 128) {
        int k = i >> 7, n = i & 127;
        W1T[n * 192 + k] = f2bf(W1[i]);
    }
    int j = i - 192 * 128;
    if (j >= 0 && j < 128 * 64) {
        int k = j >> 6, n = j & 63;
        W2T[n * 128 + k] = f2bf(W2[j]);
    }
}

// ---- bin: LDS-aggregated one-pass scatter into fixed-cap buckets -----------
__global__ __launch_bounds__(256) void bin_kernel(
    const int* __restrict__ ei, const int* __restrict__ sfi,
    int* __restrict__ bucket_cur, unsigned int* __restrict__ binned,
    int E, int Es, int N, int NB)
{
    __shared__ int hist[NB_MAX];      // per-block count, then rank cursor
    __shared__ int base_sh[NB_MAX];   // within-bucket reserved base

    int t = threadIdx.x;
    int tile0 = blockIdx.x * TILE_SRC;

    for (int b = t; b < NB; b += 256) hist[b] = 0;
    __syncthreads();

    // phase 1: histogram of bucket ids for this tile
#pragma unroll
    for (int u = 0; u < 16; ++u) {
        int src = tile0 + u * 256 + t;
        if (src < E) {
            atomicAdd(&hist[((unsigned)ei[E + src]) >> R_BITS], 1);
            atomicAdd(&hist[((unsigned)(2 * N + ei[src])) >> R_BITS], 1);
        } else if (src < E + Es) {
            int e = src - E;
            atomicAdd(&hist[((unsigned)(N + sfi[e])) >> R_BITS], 1);
            atomicAdd(&hist[((unsigned)(N + sfi[Es + e])) >> R_BITS], 1);
        }
    }
    __syncthreads();

    // phase 2: reserve per-bucket ranges; reset hist for ranking
    for (int b = t; b < NB; b += 256) {
        int c = hist[b];
        base_sh[b] = (c > 0) ? atomicAdd(&bucket_cur[b], c) : 0;
        hist[b] = 0;
    }
    __syncthreads();

    // phase 3: rank + write packed entries (per-(block,bucket) runs)
#pragma unroll
    for (int u = 0; u < 16; ++u) {
        int src = tile0 + u * 256 + t;
        if (src >= E + Es) continue;
        unsigned int g0, g1, e;
        if (src < E) {
            e = (unsigned)src;
            g0 = (unsigned)ei[E + src];
            g1 = (unsigned)(2 * N + ei[src]);
        } else {
            e = (unsigned)(src - E);
            g0 = (unsigned)(N + sfi[e]);
            g1 = (unsigned)(N + sfi[Es + e]);
        }
        int b0 = g0 >> R_BITS, b1 = g1 >> R_BITS;
        int r0 = base_sh[b0] + atomicAdd(&hist[b0], 1);
        if (r0 < CAP) binned[(size_t)b0 * CAP + r0] = ((g0 & (R - 1)) << 20) | e;
        int r1 = base_sh[b1] + atomicAdd(&hist[b1], 1);
        if (r1 < CAP) binned[(size_t)b1 * CAP + r1] = ((g1 & (R - 1)) << 20) | e;
    }
}

// ---- per-bucket: LDS counting-sort by local key, then per-key wave gather --
// 512 threads = 8 waves; wave w owns keys [w*8, w*8+8). flow out is bf16.
__global__ __launch_bounds__(512) void gather_sort_kernel(
    const float* __restrict__ edge_attr, const float* __restrict__ sf_attr,
    const unsigned int* __restrict__ binned, const int* __restrict__ bucket_cur,
    unsigned short* __restrict__ flow, int N, int T)
{
    __shared__ unsigned int stage[CAP];   // 8 KB
    __shared__ unsigned int slist[CAP];   // 8 KB (edge ids, key-sorted)
    __shared__ int kcnt[R];
    __shared__ int kstart[R];
    __shared__ int kcur[R];

    int b = blockIdx.x;
    int t = threadIdx.x;
    int w = t >> 6;         // wave 0..7
    int lane = t & 63;
    int slot = lane >> 4;   // 0..3 : edge slot within group of 4
    int quad = lane & 15;   // 0..15 : float4 index within 64-f row

    if (t < R) kcnt[t] = 0;
    __syncthreads();

    int cb = bucket_cur[b];
    if (cb > CAP) cb = CAP;

    // stage entries + per-key histogram
    for (int i = t; i < cb; i += 512) {
        unsigned int p = binned[(size_t)b * CAP + i];
        stage[i] = p;
        atomicAdd(&kcnt[p >> 20], 1);
    }
    __syncthreads();

    // 64-lane exclusive scan of kcnt (wave 0)
    if (t < R) {
        int c = kcnt[t];
        int v = c;
#pragma unroll
        for (int d = 1; d < 64; d <<= 1) {
            int x = __shfl_up(v, d);
            if (t >= d) v += x;
        }
        kstart[t] = v - c;
        kcur[t]   = v - c;
    }
    __syncthreads();

    // scatter edge ids into key-sorted LDS list
    for (int i = t; i < cb; i += 512) {
        unsigned int p = stage[i];
        int r = atomicAdd(&kcur[p >> 20], 1);
        slist[r] = p & 0xFFFFFu;
    }
    __syncthreads();

    // per-key gather: wave w owns keys [w*8, w*8+8)
    for (int kk = w * 8; kk < w * 8 + 8; ++kk) {
        int g = (b << R_BITS) + kk;
        if (g >= T) break;
        int s = (g >= 2 * N) ? 2 : ((g >= N) ? 1 : 0);
        int node = g - s * N;
        const float4* attr4 =
            reinterpret_cast<const float4*>((s == 1) ? sf_attr : edge_attr);

        int start = kstart[kk];
        int deg   = kcnt[kk];
        int end   = start + deg;

        float ax = 0.f, ay = 0.f, az = 0.f, aw = 0.f;
        int k = start;
        for (; k + 32 <= end; k += 32) {   // 8 rows in flight per lane
            unsigned int e0 = slist[k + slot];
            unsigned int e1 = slist[k + 4 + slot];
            unsigned int e2 = slist[k + 8 + slot];
            unsigned int e3 = slist[k + 12 + slot];
            unsigned int e4 = slist[k + 16 + slot];
            unsigned int e5 = slist[k + 20 + slot];
            unsigned int e6 = slist[k + 24 + slot];
            unsigned int e7 = slist[k + 28 + slot];
            float4 v0 = attr4[(size_t)e0 * 16 + quad];
            float4 v1 = attr4[(size_t)e1 * 16 + quad];
            float4 v2 = attr4[(size_t)e2 * 16 + quad];
            float4 v3 = attr4[(size_t)e3 * 16 + quad];
            float4 v4 = attr4[(size_t)e4 * 16 + quad];
            float4 v5 = attr4[(size_t)e5 * 16 + quad];
            float4 v6 = attr4[(size_t)e6 * 16 + quad];
            float4 v7 = attr4[(size_t)e7 * 16 + quad];
            ax += (v0.x + v1.x) + (v2.x + v3.x) + (v4.x + v5.x) + (v6.x + v7.x);
            ay += (v0.y + v1.y) + (v2.y + v3.y) + (v4.y + v5.y) + (v6.y + v7.y);
            az += (v0.z + v1.z) + (v2.z + v3.z) + (v4.z + v5.z) + (v6.z + v7.z);
            aw += (v0.w + v1.w) + (v2.w + v3.w) + (v4.w + v5.w) + (v6.w + v7.w);
        }
        for (; k + 16 <= end; k += 16) {   // 4 rows in flight per lane
            unsigned int e0 = slist[k + slot];
            unsigned int e1 = slist[k + 4 + slot];
            unsigned int e2 = slist[k + 8 + slot];
            unsigned int e3 = slist[k + 12 + slot];
            float4 v0 = attr4[(size_t)e0 * 16 + quad];
            float4 v1 = attr4[(size_t)e1 * 16 + quad];
            float4 v2 = attr4[(size_t)e2 * 16 + quad];
            float4 v3 = attr4[(size_t)e3 * 16 + quad];
            ax += v0.x + v1.x + v2.x + v3.x;
            ay += v0.y + v1.y + v2.y + v3.y;
            az += v0.z + v1.z + v2.z + v3.z;
            aw += v0.w + v1.w + v2.w + v3.w;
        }
        for (; k + 8 <= end; k += 8) {
            unsigned int e0 = slist[k + slot];
            unsigned int e1 = slist[k + 4 + slot];
            float4 v0 = attr4[(size_t)e0 * 16 + quad];
            float4 v1 = attr4[(size_t)e1 * 16 + quad];
            ax += v0.x + v1.x; ay += v0.y + v1.y;
            az += v0.z + v1.z; aw += v0.w + v1.w;
        }
        if (k + 4 <= end) {
            unsigned int e0 = slist[k + slot];
            float4 v0 = attr4[(size_t)e0 * 16 + quad];
            ax += v0.x; ay += v0.y; az += v0.z; aw += v0.w;
            k += 4;
        }
        if (k + slot < end) {
            unsigned int e0 = slist[k + slot];
            float4 v0 = attr4[(size_t)e0 * 16 + quad];
            ax += v0.x; ay += v0.y; az += v0.z; aw += v0.w;
        }

        // reduce across the 4 slots (lane bits 4 and 5)
        ax += __shfl_xor(ax, 16); ay += __shfl_xor(ay, 16);
        az += __shfl_xor(az, 16); aw += __shfl_xor(aw, 16);
        ax += __shfl_xor(ax, 32); ay += __shfl_xor(ay, 32);
        az += __shfl_xor(az, 32); aw += __shfl_xor(aw, 32);

        if (slot == 0) {
            float inv = 1.0f / fmaxf((float)deg, 1.0f);
            ushort4 o;
            o.x = f2bf(ax * inv);
            o.y = f2bf(ay * inv);
            o.z = f2bf(az * inv);
            o.w = f2bf(aw * inv);
            *reinterpret_cast<ushort4*>(
                &flow[(size_t)node * 192 + s * D + quad * 4]) = o;
        }
    }
}

// ---- MFMA MLP: 64 nodes/block, 4 waves ------------------------------------
// Layouts (gfx950 16x16x32 bf16, m89-verified): C/D col=lane&15,
// row=(lane>>4)*4+reg; A row=lane&15, k=(lane>>4)*8+j; B col=lane&15, same k.
#define MLP_NODES 64
#define FP 200     // ldsf row pitch (bf16): 400 B, 16B-aligned, 2-way bank alias
#define HP 136     // ldsh row pitch (bf16): 272 B

__global__ __launch_bounds__(256) void mlp_kernel(
    const unsigned short* __restrict__ flow,   // [N][192] bf16 means
    const unsigned short* __restrict__ W1T,    // [128][192] bf16
    const float* __restrict__ b1,
    const unsigned short* __restrict__ W2T,    // [64][128] bf16
    const float* __restrict__ b2,
    float* __restrict__ out, int N)
{
    __shared__ unsigned short ldsf[MLP_NODES * FP];  // 25.6 KB
    __shared__ unsigned short ldsh[MLP_NODES * HP];  // 17.4 KB

    int t = threadIdx.x;
    int nbase = blockIdx.x * MLP_NODES;

    // stage flow tile (64 nodes x 192 bf16 = 1536 x 16B)
    for (int i = t; i < 1536; i += 256) {
        int node = i / 24;
        int q    = i - node * 24;
        uint4 v = make_uint4(0u, 0u, 0u, 0u);
        if (nbase + node < N)
            v = *reinterpret_cast<const uint4*>(&flow[(size_t)(nbase + node) * 192 + q * 8]);
        *reinterpret_cast<uint4*>(&ldsf[node * FP + q * 8]) = v;
    }
    __syncthreads();

    int w   = t >> 6;
    int l   = t & 63;
    int m16 = l & 15;     // A row / B col / C col within 16x16 tile
    int kg  = l >> 4;     // k-group (k0 = kg*8), C row base = kg*4

    // ---- layer 1: M=64 (wave w owns nodes w*16..+15), Ncols=128, K=192 ----
    f32x4 acc[8];
#pragma unroll
    for (int i = 0; i < 8; ++i) acc[i] = (f32x4){0.f, 0.f, 0.f, 0.f};

#pragma unroll
    for (int kt = 0; kt < 6; ++kt) {
        bf16x8 a = *reinterpret_cast<const bf16x8*>(
            &ldsf[(w * 16 + m16) * FP + kt * 32 + kg * 8]);
#pragma unroll
        for (int nt = 0; nt < 8; ++nt) {
            bf16x8 bfr = *reinterpret_cast<const bf16x8*>(
                &W1T[(size_t)(nt * 16 + m16) * 192 + kt * 32 + kg * 8]);
            acc[nt] = __builtin_amdgcn_mfma_f32_16x16x32_bf16(a, bfr, acc[nt], 0, 0, 0);
        }
    }

    // relu + bias -> bf16 h in LDS (wave-private rows: no cross-wave dep)
#pragma unroll
    for (int nt = 0; nt < 8; ++nt) {
        int col = nt * 16 + m16;
        float bias = b1[col];
#pragma unroll
        for (int r = 0; r < 4; ++r) {
            int node = w * 16 + kg * 4 + r;
            ldsh[node * HP + col] = f2bf(fmaxf(acc[nt][r] + bias, 0.f));
        }
    }
    __syncthreads();

    // ---- layer 2: M=64, Ncols=64, K=128 ----
    f32x4 acc2[4];
#pragma unroll
    for (int i = 0; i < 4; ++i) acc2[i] = (f32x4){0.f, 0.f, 0.f, 0.f};

#pragma unroll
    for (int kt = 0; kt < 4; ++kt) {
        bf16x8 a = *reinterpret_cast<const bf16x8*>(
            &ldsh[(w * 16 + m16) * HP + kt * 32 + kg * 8]);
#pragma unroll
        for (int nt = 0; nt < 4; ++nt) {
            bf16x8 bfr = *reinterpret_cast<const bf16x8*>(
                &W2T[(size_t)(nt * 16 + m16) * 128 + kt * 32 + kg * 8]);
            acc2[nt] = __builtin_amdgcn_mfma_f32_16x16x32_bf16(a, bfr, acc2[nt], 0, 0, 0);
        }
    }

#pragma unroll
    for (int nt = 0; nt < 4; ++nt) {
        int col = nt * 16 + m16;
        float bias = b2[col];
#pragma unroll
        for (int r = 0; r < 4; ++r) {
            int node = nbase + w * 16 + kg * 4 + r;
            if (node < N)
                out[(size_t)node * D + col] = acc2[nt][r] + bias;
        }
    }
}

// ---------------------------------------------------------------------------
extern "C" void kernel_launch(void* const* d_in, const int* in_sizes, int n_in,
                              void* d_out, int out_size, void* d_ws, size_t ws_size,
                              hipStream_t stream)
{
    const int*   edge_index = (const int*)d_in[0];
    const float* edge_attr  = (const float*)d_in[1];
    const int*   sf_index   = (const int*)d_in[3];
    const float* sf_attr    = (const float*)d_in[4];
    const float* W1         = (const float*)d_in[5];
    const float* b1         = (const float*)d_in[6];
    const float* W2         = (const float*)d_in[7];
    const float* b2         = (const float*)d_in[8];
    float* out = (float*)d_out;

    int E  = in_sizes[0] / 2;
    int Es = in_sizes[3] / 2;
    int N  = out_size / D;
    int T  = 3 * N;                  // total keys
    int NB = (T + R - 1) / R;        // buckets (<= NB_MAX)

    unsigned short* flow = (unsigned short*)d_ws;          // N*192 bf16
    size_t flow_elems = (size_t)N * 192;

    unsigned int* binned = (unsigned int*)(flow + flow_elems);  // NB*CAP u32
    int* bucket_cur = (int*)(binned + (size_t)NB * CAP);        // NB
    unsigned short* W1T = (unsigned short*)(bucket_cur + NB_MAX); // 128*192
    unsigned short* W2T = W1T + 128 * 192;                        // 64*128

    hipMemsetAsync(bucket_cur, 0, (size_t)NB * sizeof(int), stream);

    wconv_kernel<<<(192 * 128 + 128 * 64 + 255) / 256, 256, 0, stream>>>(
        W1, W2, W1T, W2T);

    int nsrc = E + Es;
    int bin_blocks = (nsrc + TILE_SRC - 1) / TILE_SRC;

    bin_kernel<<<bin_blocks, 256, 0, stream>>>(
        edge_index, sf_index, bucket_cur, binned, E, Es, N, NB);

    gather_sort_kernel<<<NB, 512, 0, stream>>>(
        edge_attr, sf_attr, binned, bucket_cur, flow, N, T);

    {
        int blocks = (N + MLP_NODES - 1) / MLP_NODES;
        mlp_kernel<<<blocks, 256, 0, stream>>>(flow, W1T, b1, W2T, b2, out, N);
    }
}